// Round 1
// baseline (739.408 us; speedup 1.0000x reference)
//
#include <hip/hip_runtime.h>
#include <hip/hip_bf16.h>
#include <cstddef>

// StyleGAN2 SynthesisLayer: modulated transposed-conv (stride2, 3x3) + FIR + noise/bias/lrelu
// B=16, IC=OC=512, x 32x32 -> out 64x64.
//
// Plan: parity-decomposed dense MFMA GEMMs for the transposed conv (y 65x65, bf16 in LDS),
// separable FIR + epilogue fused in the same block. styles folded into x (pre-pass ws buffer),
// demod dcoef folded into epilogue.

typedef __attribute__((ext_vector_type(8))) short s16x8;
typedef __attribute__((ext_vector_type(4))) float f32x4;

static __device__ __forceinline__ unsigned short f2bf(float v) {
  __hip_bfloat16 h = __float2bfloat16(v);
  return __builtin_bit_cast(unsigned short, h);
}
static __device__ __forceinline__ float bf2f(unsigned short u) {
  unsigned int x = ((unsigned int)u) << 16;
  return __builtin_bit_cast(float, x);
}

// ---------------- styles[b][ic] = w[b] . (aw[ic]*wg) + ab[ic] ----------------
__global__ void k_styles(const float* __restrict__ w, const float* __restrict__ aw,
                         const float* __restrict__ ab, float* __restrict__ styles) {
  int b = blockIdx.x;
  int ic = blockIdx.y * 256 + threadIdx.x;
  const float wg = 0.044194173824159216f; // 1/sqrt(512)
  float acc = 0.f;
  const float* wp = w + b * 512;
  const float* ap = aw + (size_t)ic * 512;
  for (int d = 0; d < 512; d += 4) {
    float4 wv = *(const float4*)(wp + d);
    float4 av = *(const float4*)(ap + d);
    acc += wv.x * av.x + wv.y * av.y + wv.z * av.z + wv.w * av.w;
  }
  styles[b * 512 + ic] = acc * wg + ab[ic];
}

// ---------------- dcoefs[b][oc] = rsqrt(sum_ic s^2 * sum_k cw^2 + 1e-8) ----------------
__global__ void k_dcoef(const float* __restrict__ cw, const float* __restrict__ styles,
                        float* __restrict__ dcoefs) {
  int oc = blockIdx.x, t = threadIdx.x;
  float acc[16];
#pragma unroll
  for (int b = 0; b < 16; ++b) acc[b] = 0.f;
#pragma unroll
  for (int half = 0; half < 2; ++half) {
    int ic = half * 256 + t;
    const float* p = cw + ((size_t)oc * 512 + ic) * 9;
    float s2 = 0.f;
#pragma unroll
    for (int k = 0; k < 9; ++k) { float v = p[k]; s2 += v * v; }
#pragma unroll
    for (int b = 0; b < 16; ++b) { float s = styles[b * 512 + ic]; acc[b] += s2 * s * s; }
  }
#pragma unroll
  for (int off = 32; off > 0; off >>= 1) {
#pragma unroll
    for (int b = 0; b < 16; ++b) acc[b] += __shfl_down(acc[b], off, 64);
  }
  __shared__ float part[4][16];
  int wid = t >> 6, lane = t & 63;
  if (lane == 0) {
    for (int b = 0; b < 16; ++b) part[wid][b] = acc[b];
  }
  __syncthreads();
  if (t < 16) {
    float s = part[0][t] + part[1][t] + part[2][t] + part[3][t];
    dcoefs[t * 512 + oc] = rsqrtf(s + 1e-8f);
  }
}

// ---------------- xt[b][iy*32+ix][ic] = bf16( x[b][ic][iy][ix] * styles[b][ic] ) ----------------
__global__ void k_xt(const float* __restrict__ x, const float* __restrict__ styles,
                     unsigned short* __restrict__ xt) {
  __shared__ float tile[32][33];
  int b = blockIdx.z, icb = blockIdx.y * 32, pb = blockIdx.x * 32;
  int tp = threadIdx.x & 31, tq = threadIdx.x >> 5;
#pragma unroll
  for (int i = 0; i < 32; i += 8) {
    int ic = icb + tq + i;
    tile[tq + i][tp] = x[((size_t)(b * 512 + ic)) * 1024 + pb + tp] * styles[b * 512 + ic];
  }
  __syncthreads();
#pragma unroll
  for (int i = 0; i < 32; i += 8) {
    int p = pb + tq + i;
    xt[((size_t)(b * 1024 + p)) * 512 + icb + tp] = f2bf(tile[tp][tq + i]);
  }
}

// ---------------- main fused kernel ----------------
// block: (oc-tile 32, 16 out rows, full 64-wide), 256 threads = 4 waves.
// per parity (py outer, px pair in acc): y_sub GEMM K=IC per tap, taps {ky in py-set} x {kx}.
// y staged bf16 in LDS [32][19][68]; then separable FIR + epilogue.
__global__ __launch_bounds__(256, 1)
void k_main(const float* __restrict__ cw, const float* __restrict__ styles,
            const float* __restrict__ dcoefs, const float* __restrict__ bias,
            const float* __restrict__ noise, const unsigned short* __restrict__ xt,
            const float* __restrict__ xg, float* __restrict__ out, int use_xt) {
  __shared__ __align__(16) unsigned short lds_x[11 * 36 * 32]; // [row11][col36][ic32] swizzled
  __shared__ __align__(16) unsigned short lds_w[9 * 32 * 32];  // [tap9][oc32][ic32]  swizzled
  __shared__ __align__(16) unsigned short lds_y[32 * 19 * 68]; // [oc32][yrow19][ycol68]

  const int oc0 = blockIdx.x * 32;
  const int Y0 = blockIdx.y * 16;
  const int J0 = blockIdx.y * 8;
  const int b = blockIdx.z;
  const int tid = threadIdx.x;
  const int wid = tid >> 6;
  const int lane = tid & 63;
  const int l15 = lane & 15;
  const int l4 = lane >> 4;

  for (int py = 0; py < 2; ++py) {
    int fstart, myNF, NJY, NKY;
    if (py == 0) { fstart = wid * 5; myNF = 5; NJY = 9; NKY = 2; }
    else { fstart = (wid < 2) ? wid * 6 : 12 + (wid - 2) * 5; myNF = (wid < 2) ? 6 : 5; NJY = 10; NKY = 1; }
    const int nlim = NJY * 34;

    int rb6[6], yr6[6], jx6[6];
    bool nv6[6];
#pragma unroll
    for (int f = 0; f < 6; ++f) {
      int n = (fstart + f) * 16 + l15;
      int jy = n / 34;
      int jx = n - jy * 34;
      int jyc = jy < 9 ? jy : 9; // clamp junk lanes into staged rows
      rb6[f] = (jyc + 1) * 36 + jx;
      jx6[f] = jx;
      yr6[f] = 2 * jy + 1 - py;
      nv6[f] = (n < nlim) && (f < myNF);
    }

    f32x4 acc[2][2][6];
#pragma unroll
    for (int px = 0; px < 2; ++px)
#pragma unroll
      for (int mf = 0; mf < 2; ++mf)
#pragma unroll
        for (int f = 0; f < 6; ++f) acc[px][mf][f] = (f32x4){0.f, 0.f, 0.f, 0.f};

    const int W = J0 - 2 + (1 - py); // x-row window base (global iy of LDS row 0)

    for (int kc = 0; kc < 16; ++kc) {
      const int ic0 = kc * 32;
      __syncthreads();
      // ---- stage x~ tile: 11x36 positions x 32 ic (bf16, styles folded), zero-padded halo ----
      for (int g = tid; g < 1584; g += 256) {
        int run = g >> 2, kg = g & 3;
        int r = run / 36;
        int c = run - r * 36;
        int iy = W + r, ix = c - 2;
        s16x8 v = {0, 0, 0, 0, 0, 0, 0, 0};
        bool inr = ((unsigned)iy < 32u) && ((unsigned)ix < 32u);
        if (use_xt) {
          if (inr) v = *(const s16x8*)(xt + (((size_t)(b * 1024 + iy * 32 + ix)) * 512 + ic0 + kg * 8));
        } else {
          if (inr) {
#pragma unroll
            for (int e = 0; e < 8; ++e) {
              int ic = ic0 + kg * 8 + e;
              float xv = xg[((size_t)(b * 512 + ic)) * 1024 + iy * 32 + ix] * styles[b * 512 + ic];
              v[e] = (short)f2bf(xv);
            }
          }
        }
        *(s16x8*)(lds_x + run * 32 + ((kg ^ (run & 3)) << 3)) = v;
      }
      // ---- stage weight tile: plain conv_weight (bf16), 9 taps x 32 oc x 32 ic ----
      for (int p = tid; p < 1024; p += 256) {
        int ocr = p >> 5, icr = p & 31;
        const float* pw = cw + (((size_t)(oc0 + ocr)) * 512 + (ic0 + icr)) * 9;
#pragma unroll
        for (int t = 0; t < 9; ++t) {
          int run = t * 32 + ocr;
          lds_w[run * 32 + ((((icr >> 3) ^ (run & 3)) << 3)) + (icr & 7)] = f2bf(pw[t]);
        }
      }
      __syncthreads();
      // ---- MFMA: per ky, B-frag cols +1/+2 shared across {kx=2|px0, kx=1|px1} ----
#pragma unroll
      for (int kyi = 0; kyi < 2; ++kyi) {
        if (kyi < NKY) {
          const int ky = py ? 1 : kyi * 2;
          const int dyo = ky >> 1;
          s16x8 a[3][2];
#pragma unroll
          for (int kx = 0; kx < 3; ++kx)
#pragma unroll
            for (int mf = 0; mf < 2; ++mf) {
              int run = (ky * 3 + kx) * 32 + mf * 16 + l15;
              a[kx][mf] = *(const s16x8*)(lds_w + run * 32 + ((l4 ^ (run & 3)) << 3));
            }
#pragma unroll
          for (int f = 0; f < 6; ++f) {
            if (f < myNF) {
              int r1 = rb6[f] - dyo * 36 + 1;
              int r2 = r1 + 1;
              s16x8 b1 = *(const s16x8*)(lds_x + r1 * 32 + ((l4 ^ (r1 & 3)) << 3));
              s16x8 b2 = *(const s16x8*)(lds_x + r2 * 32 + ((l4 ^ (r2 & 3)) << 3));
#pragma unroll
              for (int mf = 0; mf < 2; ++mf) {
                acc[0][mf][f] = __builtin_amdgcn_mfma_f32_16x16x32_bf16(a[0][mf], b2, acc[0][mf][f], 0, 0, 0);
                acc[0][mf][f] = __builtin_amdgcn_mfma_f32_16x16x32_bf16(a[2][mf], b1, acc[0][mf][f], 0, 0, 0);
                acc[1][mf][f] = __builtin_amdgcn_mfma_f32_16x16x32_bf16(a[1][mf], b1, acc[1][mf][f], 0, 0, 0);
              }
            }
          }
        }
      }
    }
    // ---- dump y_sub (both px) into y-LDS ----
#pragma unroll
    for (int f = 0; f < 6; ++f) {
      if (nv6[f]) {
#pragma unroll
        for (int px = 0; px < 2; ++px) {
          int ycol = 2 * jx6[f] + 1 - px;
#pragma unroll
          for (int mf = 0; mf < 2; ++mf)
#pragma unroll
            for (int r = 0; r < 4; ++r) {
              int ocr = mf * 16 + l4 * 4 + r;
              lds_y[(ocr * 19 + yr6[f]) * 68 + ycol] = f2bf(acc[px][mf][f][r]);
            }
        }
      }
    }
  }
  __syncthreads();
  // ---- FIR vertical pass (in place, column-private) ----
  for (int task = tid; task < 2176; task += 256) {
    int ocr = task / 68;
    int c = task - ocr * 68;
    unsigned short* colp = lds_y + ocr * 1292 + c;
    float vt[16];
    float y0 = bf2f(colp[0]), y1 = bf2f(colp[68]), y2 = bf2f(colp[136]);
#pragma unroll
    for (int Y = 0; Y < 16; ++Y) {
      float y3 = bf2f(colp[(Y + 3) * 68]);
      vt[Y] = 0.25f * (y0 + y3) + 0.75f * (y1 + y2);
      y0 = y1; y1 = y2; y2 = y3;
    }
#pragma unroll
    for (int Y = 0; Y < 16; ++Y) colp[Y * 68] = f2bf(vt[Y]);
  }
  __syncthreads();
  // ---- FIR horizontal pass + demod + noise + bias + lrelu*sqrt(2) ----
  for (int task = tid; task < 2048; task += 256) {
    int ocr = task >> 6;
    int rem = task & 63;
    int Y = rem >> 2, q = rem & 3;
    const unsigned short* rowp = lds_y + ocr * 1292 + Y * 68 + q * 16;
    float vb[19];
#pragma unroll
    for (int u = 0; u < 19; ++u) vb[u] = bf2f(rowp[u]);
    int ocg = oc0 + ocr, Yg = Y0 + Y, Xg = q * 16;
    float dc = dcoefs[b * 512 + ocg];
    float bv = bias[ocg];
    const float* np = noise + Yg * 64 + Xg;
    float* op = out + (((size_t)(b * 512 + ocg)) * 64 + Yg) * 64 + Xg;
#pragma unroll
    for (int xx = 0; xx < 16; ++xx) {
      float o = 0.25f * (vb[xx] + vb[xx + 3]) + 0.75f * (vb[xx + 1] + vb[xx + 2]);
      o = o * dc + np[xx] + bv;
      o = (o > 0.f ? o : 0.2f * o) * 1.4142135623730951f;
      op[xx] = o;
    }
  }
}

extern "C" void kernel_launch(void* const* d_in, const int* in_sizes, int n_in,
                              void* d_out, int out_size, void* d_ws, size_t ws_size,
                              hipStream_t stream) {
  const float* x = (const float*)d_in[0];      // [16,512,32,32]
  const float* w = (const float*)d_in[1];      // [16,512]
  const float* aw = (const float*)d_in[2];     // [512,512]
  const float* ab = (const float*)d_in[3];     // [512]
  const float* cw = (const float*)d_in[4];     // [512,512,3,3]
  const float* bias = (const float*)d_in[5];   // [512]
  const float* noise = (const float*)d_in[6];  // [64,64]
  // d_in[7] = FIR f (4x4). Deterministic from setup: separable [.25,.75,.75,.25] per dim (gain folded).
  float* out = (float*)d_out;

  float* styles = (float*)d_ws;                 // 16*512 f32
  float* dcoefs = styles + 16 * 512;            // 16*512 f32
  unsigned short* xt = (unsigned short*)((char*)d_ws + 65536); // 16*1024*512 bf16
  size_t need = 65536 + (size_t)16 * 1024 * 512 * 2;
  int use_xt = (ws_size >= need) ? 1 : 0;

  k_styles<<<dim3(16, 2), 256, 0, stream>>>(w, aw, ab, styles);
  k_dcoef<<<dim3(512), 256, 0, stream>>>(cw, styles, dcoefs);
  if (use_xt) k_xt<<<dim3(32, 16, 16), 256, 0, stream>>>(x, styles, xt);
  k_main<<<dim3(16, 4, 16), 256, 0, stream>>>(cw, styles, dcoefs, bias, noise, xt, x, out, use_xt);
}

// Round 2
// 305.437 us; speedup vs baseline: 2.4208x; 2.4208x over previous
//
#include <hip/hip_runtime.h>
#include <hip/hip_bf16.h>
#include <cstddef>
#include <cstdint>

// StyleGAN2 SynthesisLayer fused: modulated transposed-conv (stride2 3x3) + FIR + noise/bias/lrelu
// Round 2: single-pass dual-parity K-loop, 57KB LDS (2 blocks/CU), global_load_lds staging from
// pre-transformed bf16 buffers, 80B conflict-free LDS rows, XCD swizzle.

typedef __attribute__((ext_vector_type(8))) short s16x8;
typedef __attribute__((ext_vector_type(4))) short s16x4;
typedef __attribute__((ext_vector_type(4))) float f32x4;

static __device__ __forceinline__ unsigned short f2bf(float v) {
  __hip_bfloat16 h = __float2bfloat16(v);
  return __builtin_bit_cast(unsigned short, h);
}
static __device__ __forceinline__ float bf2f(unsigned short u) {
  unsigned int x = ((unsigned int)u) << 16;
  return __builtin_bit_cast(float, x);
}

static __device__ __forceinline__ void gload16(const void* g, const void* l) {
  __builtin_amdgcn_global_load_lds((const __attribute__((address_space(1))) unsigned int*)g,
                                   (__attribute__((address_space(3))) unsigned int*)l, 16, 0, 0);
}

// ---------------- styles[b][ic] = w[b] . (aw[ic]*wg) + ab[ic] ----------------
__global__ void k_styles(const float* __restrict__ w, const float* __restrict__ aw,
                         const float* __restrict__ ab, float* __restrict__ styles) {
  int b = blockIdx.x;
  int ic = blockIdx.y * 32 + (threadIdx.x >> 3);
  int l = threadIdx.x & 7;
  const float wg = 0.044194173824159216f; // 1/sqrt(512)
  const float* wp = w + b * 512 + l * 64;
  const float* ap = aw + (size_t)ic * 512 + l * 64;
  float s = 0.f;
  for (int d = 0; d < 64; d += 4) {
    float4 wv = *(const float4*)(wp + d);
    float4 av = *(const float4*)(ap + d);
    s += wv.x * av.x + wv.y * av.y + wv.z * av.z + wv.w * av.w;
  }
  s += __shfl_down(s, 4, 64);
  s += __shfl_down(s, 2, 64);
  s += __shfl_down(s, 1, 64);
  if (l == 0) styles[b * 512 + ic] = s * wg + ab[ic];
}

// ------- per-oc: write wt[oc][tap][ic] (bf16) + dcoefs[b][oc] -------
__global__ void k_wt_dcoef(const float* __restrict__ cw, const float* __restrict__ styles,
                           unsigned short* __restrict__ wt, float* __restrict__ dcoefs,
                           int do_wt) {
  __shared__ float lw[4608];
  __shared__ float part[4][16];
  int oc = blockIdx.x, t = threadIdx.x;
  for (int k = t; k < 4608; k += 256) lw[k] = cw[(size_t)oc * 4608 + k];
  __syncthreads();
  if (do_wt) {
    for (int c = t; c < 576; c += 256) {
      int tap = c >> 6, icc = c & 63;
      s16x8 v;
#pragma unroll
      for (int e = 0; e < 8; ++e) v[e] = (short)f2bf(lw[(icc * 8 + e) * 9 + tap]);
      *(s16x8*)(wt + ((size_t)oc * 9 + tap) * 512 + icc * 8) = v;
    }
  }
  float acc[16];
#pragma unroll
  for (int b2 = 0; b2 < 16; ++b2) acc[b2] = 0.f;
#pragma unroll
  for (int j = 0; j < 2; ++j) {
    int ic = t * 2 + j;
    float s2 = 0.f;
#pragma unroll
    for (int k = 0; k < 9; ++k) { float v = lw[ic * 9 + k]; s2 += v * v; }
#pragma unroll
    for (int b2 = 0; b2 < 16; ++b2) { float s = styles[b2 * 512 + ic]; acc[b2] += s2 * s * s; }
  }
#pragma unroll
  for (int off = 32; off > 0; off >>= 1) {
#pragma unroll
    for (int b2 = 0; b2 < 16; ++b2) acc[b2] += __shfl_down(acc[b2], off, 64);
  }
  int wid = t >> 6, lane = t & 63;
  if (lane == 0) {
    for (int b2 = 0; b2 < 16; ++b2) part[wid][b2] = acc[b2];
  }
  __syncthreads();
  if (t < 16) {
    float s = part[0][t] + part[1][t] + part[2][t] + part[3][t];
    dcoefs[t * 512 + oc] = rsqrtf(s + 1e-8f);
  }
}

// ------- padded modulated x: xtp[b][36][36][512] bf16, zero halo (pad 2 each side) -------
__global__ void k_xt(const float* __restrict__ x, const float* __restrict__ styles,
                     unsigned short* __restrict__ xtp) {
  __shared__ __align__(16) unsigned short trans[32][520];
  int pr = blockIdx.x, b = blockIdx.y, t = threadIdx.x;
  bool interior = (pr >= 2 && pr < 34);
  if (interior) {
    int iy = pr - 2;
#pragma unroll 4
    for (int i = 0; i < 64; ++i) {
      int idx = t + i * 256;
      int ic = idx >> 5, ix = idx & 31;
      float v = x[((size_t)(b * 512 + ic)) * 1024 + iy * 32 + ix] * styles[b * 512 + ic];
      trans[ix][ic] = f2bf(v);
    }
  }
  __syncthreads();
  for (int c = t; c < 2304; c += 256) {
    int pc = c >> 6, icc = c & 63;
    s16x8 v = {0, 0, 0, 0, 0, 0, 0, 0};
    if (interior && pc >= 2 && pc < 34) v = *(const s16x8*)&trans[pc - 2][icc * 8];
    *(s16x8*)(xtp + ((size_t)(b * 1296 + pr * 36 + pc)) * 512 + icc * 8) = v;
  }
}

// ---------------- main fused kernel ----------------
// LDS: stage area  = lds_x [432 runs][80B] (padded to 34816) + lds_w [288 runs][80B] (pad to 23552)
//      epilogue    = lds_y [16][19][68] bf16 (43520) aliased over stage area. total 58368B.
// runs: x: run = r*36 + c (12 rows x 36 cols window, rows J0-2..J0+9 global iy, col-2..33 ix)
//       w: run = tap*32 + ocr
template <int PRE>
__global__ __launch_bounds__(256, 2)
void k_main(const unsigned short* __restrict__ xtp, const unsigned short* __restrict__ wtp,
            const float* __restrict__ xg, const float* __restrict__ cw,
            const float* __restrict__ styles, const float* __restrict__ dcoefs,
            const float* __restrict__ bias, const float* __restrict__ noise,
            float* __restrict__ out) {
  __shared__ __align__(16) unsigned char smem[58368];

  int bid = blockIdx.x;
  int q8 = (bid >> 3) + (bid & 7) * 128;  // XCD-contiguous remap (1024 = 8*128)
  const int ocT = q8 & 15, yT = (q8 >> 4) & 3, b = q8 >> 6;
  const int oc0 = ocT * 32;
  const int J0 = yT * 8, Y0 = yT * 16;
  const int tid = threadIdx.x, wid = tid >> 6, lane = tid & 63;
  const int l15 = lane & 15, l4 = lane >> 4;

  // frag geometry: py0 grid 9x34 (306 pos, 20 frags, 5/wave); py1 grid 10x34 (340 pos, 22 frags)
  const int fs1 = (wid < 2) ? wid * 6 : 12 + (wid - 2) * 5;
  const int NF1 = (wid < 2) ? 6 : 5;
  int bb0[5], bb1[6];
#pragma unroll
  for (int f = 0; f < 5; ++f) {
    int n = (wid * 5 + f) * 16 + l15;
    int jy = n / 34, jx = n - jy * 34;
    bb0[f] = ((jy + 1) * 36 + jx + 1) * 80 + l4 * 16;
  }
#pragma unroll
  for (int f = 0; f < 6; ++f) {
    int n = (fs1 + f) * 16 + l15;
    int jy = n / 34, jx = n - jy * 34;
    bb1[f] = ((jy + 1) * 36 + jx + 1) * 80 + l4 * 16;
  }
  const int aoffB = l15 * 80 + l4 * 16;

  f32x4 acc0[2][2][5];  // [px][mf][f]  (py0: odd y rows)
  f32x4 acc1[2][2][6];  // [px][mf][f]  (py1: even y rows)
#pragma unroll
  for (int px = 0; px < 2; ++px)
#pragma unroll
    for (int mf = 0; mf < 2; ++mf) {
#pragma unroll
      for (int f = 0; f < 5; ++f) acc0[px][mf][f] = (f32x4){0.f, 0.f, 0.f, 0.f};
#pragma unroll
      for (int f = 0; f < 6; ++f) acc1[px][mf][f] = (f32x4){0.f, 0.f, 0.f, 0.f};
    }

  const char* LX = (const char*)smem;
  const char* LW = (const char*)smem + 34816;

  for (int kc = 0; kc < 16; ++kc) {
    const int ic0 = kc * 32;
    __syncthreads();
    if (PRE) {
      // x: 2160 chunks (432 runs x 5 slots: 4 data + 1 pad) -> 34 wave-instrs
      const unsigned short* xsb = xtp + ((size_t)(b * 1296 + J0 * 36)) * 512 + ic0;
      for (int i = wid; i < 34; i += 4) {
        int q = i * 64 + lane;
        int q2 = q < 2159 ? q : 2159;
        int run = q2 / 5;
        int c = q2 - run * 5; c = c > 3 ? 3 : c;
        gload16(xsb + run * 512 + c * 8, smem + i * 1024);
      }
      // w: 1440 chunks (288 runs x 5) -> 23 wave-instrs
      const unsigned short* wsb = wtp + (size_t)oc0 * 4608 + ic0;
      for (int i = wid; i < 23; i += 4) {
        int q = i * 64 + lane;
        int q2 = q < 1439 ? q : 1439;
        int run = q2 / 5;
        int c = q2 - run * 5; c = c > 3 ? 3 : c;
        int tap = run >> 5, ocr = run & 31;
        gload16(wsb + (size_t)ocr * 4608 + tap * 512 + c * 8, smem + 34816 + i * 1024);
      }
      asm volatile("s_waitcnt vmcnt(0)" ::: "memory");
    } else {
      // fallback: manual modulate+convert staging (slow path, correctness safety)
      for (int s = tid; s < 1728; s += 256) {
        int run = s >> 2, c = s & 3;
        int r = run / 36, cc = run - r * 36;
        int iy = J0 + r - 2, ix = cc - 2;
        s16x8 v = {0, 0, 0, 0, 0, 0, 0, 0};
        if ((unsigned)iy < 32u && (unsigned)ix < 32u) {
#pragma unroll
          for (int e = 0; e < 8; ++e) {
            int ic = ic0 + c * 8 + e;
            v[e] = (short)f2bf(xg[((size_t)(b * 512 + ic)) * 1024 + iy * 32 + ix] * styles[b * 512 + ic]);
          }
        }
        *(s16x8*)((char*)smem + run * 80 + c * 16) = v;
      }
      for (int s = tid; s < 1152; s += 256) {
        int run = s >> 2, c = s & 3;
        int tap = run >> 5, ocr = run & 31;
        s16x8 v;
#pragma unroll
        for (int e = 0; e < 8; ++e)
          v[e] = (short)f2bf(cw[((size_t)(oc0 + ocr) * 512 + ic0 + c * 8 + e) * 9 + tap]);
        *(s16x8*)((char*)smem + 34816 + run * 80 + c * 16) = v;
      }
    }
    __syncthreads();

    const char* aw_ = LW + aoffB;
    // ---- py0, ky=0 (taps 0..2): B rows jy+2 -> offsets +2880/+2960
    {
      s16x8 A[3][2];
#pragma unroll
      for (int kx = 0; kx < 3; ++kx)
#pragma unroll
        for (int mf = 0; mf < 2; ++mf) A[kx][mf] = *(const s16x8*)(aw_ + kx * 2560 + mf * 1280);
#pragma unroll
      for (int f = 0; f < 5; ++f) {
        const char* bp = LX + bb0[f];
        s16x8 B3 = *(const s16x8*)(bp + 2880);
        s16x8 B4 = *(const s16x8*)(bp + 2960);
#pragma unroll
        for (int mf = 0; mf < 2; ++mf) {
          acc0[0][mf][f] = __builtin_amdgcn_mfma_f32_16x16x32_bf16(A[0][mf], B4, acc0[0][mf][f], 0, 0, 0);
          acc0[0][mf][f] = __builtin_amdgcn_mfma_f32_16x16x32_bf16(A[2][mf], B3, acc0[0][mf][f], 0, 0, 0);
          acc0[1][mf][f] = __builtin_amdgcn_mfma_f32_16x16x32_bf16(A[1][mf], B3, acc0[1][mf][f], 0, 0, 0);
        }
      }
    }
    // ---- py0, ky=2 (taps 6..8): B rows jy+1 -> offsets +0/+80
    {
      s16x8 A[3][2];
#pragma unroll
      for (int kx = 0; kx < 3; ++kx)
#pragma unroll
        for (int mf = 0; mf < 2; ++mf) A[kx][mf] = *(const s16x8*)(aw_ + (6 + kx) * 2560 + mf * 1280);
#pragma unroll
      for (int f = 0; f < 5; ++f) {
        const char* bp = LX + bb0[f];
        s16x8 B1 = *(const s16x8*)(bp);
        s16x8 B2 = *(const s16x8*)(bp + 80);
#pragma unroll
        for (int mf = 0; mf < 2; ++mf) {
          acc0[0][mf][f] = __builtin_amdgcn_mfma_f32_16x16x32_bf16(A[0][mf], B2, acc0[0][mf][f], 0, 0, 0);
          acc0[0][mf][f] = __builtin_amdgcn_mfma_f32_16x16x32_bf16(A[2][mf], B1, acc0[0][mf][f], 0, 0, 0);
          acc0[1][mf][f] = __builtin_amdgcn_mfma_f32_16x16x32_bf16(A[1][mf], B1, acc0[1][mf][f], 0, 0, 0);
        }
      }
    }
    // ---- py1, ky=1 (taps 3..5): B rows jy+1 -> offsets +0/+80
    {
      s16x8 A[3][2];
#pragma unroll
      for (int kx = 0; kx < 3; ++kx)
#pragma unroll
        for (int mf = 0; mf < 2; ++mf) A[kx][mf] = *(const s16x8*)(aw_ + (3 + kx) * 2560 + mf * 1280);
#pragma unroll
      for (int f = 0; f < 6; ++f) {
        if (f < NF1) {
          const char* bp = LX + bb1[f];
          s16x8 B1 = *(const s16x8*)(bp);
          s16x8 B2 = *(const s16x8*)(bp + 80);
#pragma unroll
          for (int mf = 0; mf < 2; ++mf) {
            acc1[0][mf][f] = __builtin_amdgcn_mfma_f32_16x16x32_bf16(A[0][mf], B2, acc1[0][mf][f], 0, 0, 0);
            acc1[0][mf][f] = __builtin_amdgcn_mfma_f32_16x16x32_bf16(A[2][mf], B1, acc1[0][mf][f], 0, 0, 0);
            acc1[1][mf][f] = __builtin_amdgcn_mfma_f32_16x16x32_bf16(A[1][mf], B1, acc1[1][mf][f], 0, 0, 0);
          }
        }
      }
    }
  }

  // ---- epilogue: per oc-half: dump y (bf16) -> vertical FIR -> horizontal FIR + store ----
  unsigned short* ly = (unsigned short*)smem;  // [16][19][68]
#pragma unroll
  for (int mf = 0; mf < 2; ++mf) {
    __syncthreads();
#pragma unroll
    for (int f = 0; f < 5; ++f) {
      int n = (wid * 5 + f) * 16 + l15;
      if (n < 306) {
        int jy = n / 34, jx = n - jy * 34;
        int yr = 2 * jy + 1;
#pragma unroll
        for (int px = 0; px < 2; ++px) {
          int yc = 2 * jx + 1 - px;
#pragma unroll
          for (int r = 0; r < 4; ++r)
            ly[(l4 * 4 + r) * 1292 + yr * 68 + yc] = f2bf(acc0[px][mf][f][r]);
        }
      }
    }
#pragma unroll
    for (int f = 0; f < 6; ++f) {
      if (f < NF1) {
        int n = (fs1 + f) * 16 + l15;
        if (n < 340) {
          int jy = n / 34, jx = n - jy * 34;
          int yr = 2 * jy;
#pragma unroll
          for (int px = 0; px < 2; ++px) {
            int yc = 2 * jx + 1 - px;
#pragma unroll
            for (int r = 0; r < 4; ++r)
              ly[(l4 * 4 + r) * 1292 + yr * 68 + yc] = f2bf(acc1[px][mf][f][r]);
          }
        }
      }
    }
    __syncthreads();
    for (int task = tid; task < 1088; task += 256) {
      int ocr = task / 68;
      int c2 = task - ocr * 68;
      unsigned short* colp = ly + ocr * 1292 + c2;
      float y0 = bf2f(colp[0]), y1 = bf2f(colp[68]), y2 = bf2f(colp[136]);
      float vt[16];
#pragma unroll
      for (int Y = 0; Y < 16; ++Y) {
        float y3 = bf2f(colp[(Y + 3) * 68]);
        vt[Y] = 0.25f * (y0 + y3) + 0.75f * (y1 + y2);
        y0 = y1; y1 = y2; y2 = y3;
      }
#pragma unroll
      for (int Y = 0; Y < 16; ++Y) colp[Y * 68] = f2bf(vt[Y]);
    }
    __syncthreads();
    for (int task = tid; task < 1024; task += 256) {
      int ocr = task >> 6, rem = task & 63;
      int Y = rem >> 2, qq = rem & 3;
      const unsigned short* rowp = ly + ocr * 1292 + Y * 68 + qq * 16;
      float vb[20];
#pragma unroll
      for (int k = 0; k < 5; ++k) {
        s16x4 ch = *(const s16x4*)(rowp + k * 4);
#pragma unroll
        for (int j2 = 0; j2 < 4; ++j2) vb[k * 4 + j2] = bf2f((unsigned short)ch[j2]);
      }
      int oc = oc0 + mf * 16 + ocr;
      int Yg = Y0 + Y, Xg = qq * 16;
      float dc = dcoefs[b * 512 + oc];
      float bv = bias[oc];
      const float* np = noise + Yg * 64 + Xg;
      float* op = out + (((size_t)(b * 512 + oc)) * 64 + Yg) * 64 + Xg;
#pragma unroll
      for (int xx = 0; xx < 16; ++xx) {
        float o = 0.25f * (vb[xx] + vb[xx + 3]) + 0.75f * (vb[xx + 1] + vb[xx + 2]);
        o = o * dc + np[xx] + bv;
        o = (o > 0.f ? o : 0.2f * o) * 1.4142135623730951f;
        op[xx] = o;
      }
    }
  }
}

extern "C" void kernel_launch(void* const* d_in, const int* in_sizes, int n_in,
                              void* d_out, int out_size, void* d_ws, size_t ws_size,
                              hipStream_t stream) {
  const float* x = (const float*)d_in[0];      // [16,512,32,32]
  const float* w = (const float*)d_in[1];      // [16,512]
  const float* aw = (const float*)d_in[2];     // [512,512]
  const float* ab = (const float*)d_in[3];     // [512]
  const float* cw = (const float*)d_in[4];     // [512,512,3,3]
  const float* bias = (const float*)d_in[5];   // [512]
  const float* noise = (const float*)d_in[6];  // [64,64]
  float* out = (float*)d_out;

  float* styles = (float*)d_ws;                                   // 8192 f32
  float* dcoefs = styles + 8192;                                  // 8192 f32
  unsigned short* xtp = (unsigned short*)((char*)d_ws + 65536);   // 16*1296*512 bf16
  unsigned short* wtp = xtp + (size_t)16 * 1296 * 512;            // 512*9*512 bf16
  size_t need = 65536 + (size_t)16 * 1296 * 512 * 2 + (size_t)512 * 9 * 512 * 2;
  int pre = (ws_size >= need) ? 1 : 0;

  k_styles<<<dim3(16, 16), 256, 0, stream>>>(w, aw, ab, styles);
  k_wt_dcoef<<<dim3(512), 256, 0, stream>>>(cw, styles, wtp, dcoefs, pre);
  if (pre) {
    k_xt<<<dim3(36, 16), 256, 0, stream>>>(x, styles, xtp);
    k_main<1><<<dim3(1024), 256, 0, stream>>>(xtp, wtp, x, cw, styles, dcoefs, bias, noise, out);
  } else {
    k_main<0><<<dim3(1024), 256, 0, stream>>>(xtp, wtp, x, cw, styles, dcoefs, bias, noise, out);
  }
}